// Round 1
// baseline (9422.584 us; speedup 1.0000x reference)
//
#include <hip/hip_runtime.h>
#include <hip/hip_bf16.h>
#include <cstdint>
#include <cstddef>

#define NT 512   // timesteps
#define NB 256   // batch
#define NF 1024  // IN_F
#define NH 1024  // HID
#define NC 512   // NCLS

typedef __attribute__((ext_vector_type(8))) short short8;
typedef __attribute__((ext_vector_type(4))) float f32x4;

static __device__ __forceinline__ unsigned short f2bf(float f) {
  union { float f; unsigned int u; } x; x.f = f;
  return (unsigned short)((x.u + 0x7FFFu + ((x.u >> 16) & 1u)) >> 16);  // RNE
}
static __device__ __forceinline__ float bf2f(unsigned short h) {
  union { unsigned int u; float f; } x; x.u = ((unsigned int)h) << 16;
  return x.f;
}
static __device__ __forceinline__ float fast_tanh(float x) {
  // 1 - 2/(e^{2x}+1): exact algebra, no overflow (e->inf => 1, e->0 => -1)
  float e = __expf(2.0f * x);
  return 1.0f - 2.0f / (e + 1.0f);
}

// ---- LDS staging (xor-swizzled 16B blocks; tile = ROWS x BKW bf16, K contiguous) ----
template<int ROWS, int BKW, int THREADS>
static __device__ __forceinline__ void stage_bf16(const unsigned short* __restrict__ g,
                                                  int ldg, unsigned short* lds, int tid) {
  constexpr int UPR = BKW / 8;  // 16B units per row
  constexpr int UNITS = ROWS * UPR;
  #pragma unroll
  for (int e = tid; e < UNITS; e += THREADS) {
    int row = e / UPR;
    int u = e % UPR;
    uint4 v = *(const uint4*)(g + (size_t)row * ldg + u * 8);
    int su = u ^ (row & (UPR - 1));
    *(uint4*)(lds + row * BKW + su * 8) = v;
  }
}

template<int ROWS, int BKW, int THREADS>
static __device__ __forceinline__ void stage_f32_to_bf16(const float* __restrict__ g,
                                                         int ldg, unsigned short* lds, int tid) {
  constexpr int UPR = BKW / 4;  // float4 units per row
  constexpr int UNITS = ROWS * UPR;
  #pragma unroll
  for (int e = tid; e < UNITS; e += THREADS) {
    int row = e / UPR;
    int u = e % UPR;
    float4 v = *(const float4*)(g + (size_t)row * ldg + u * 4);
    ushort4 p;
    p.x = f2bf(v.x); p.y = f2bf(v.y); p.z = f2bf(v.z); p.w = f2bf(v.w);
    int sb = (u >> 1) ^ (row & (BKW / 8 - 1));
    *(ushort4*)(lds + row * BKW + sb * 8 + (u & 1) * 4) = p;
  }
}

template<int BKW>
static __device__ __forceinline__ short8 frag_ld(const unsigned short* lds, int row, int kbase) {
  int blk = (kbase >> 3) ^ (row & (BKW / 8 - 1));
  return *(const short8*)(lds + row * BKW + blk * 8);
}

// ---- prep: fp32 -> bf16 weight conversion into ws ----
__global__ void prep_kernel(const float* __restrict__ Wih, const float* __restrict__ Who,
                            const float* __restrict__ h0f,
                            unsigned short* __restrict__ Wx, unsigned short* __restrict__ Wh,
                            unsigned short* __restrict__ Wo, unsigned short* __restrict__ h0) {
  int i = blockIdx.x * 256 + threadIdx.x;  // grid = 4096*256 = 1M exactly
  int r = i >> 10, c = i & 1023;
  Wx[i] = f2bf(Wih[(size_t)r * 2048 + c]);
  Wh[i] = f2bf(Wih[(size_t)r * 2048 + 1024 + c]);
  if (i < 512 * 1024) Wo[i] = f2bf(Who[i]);
  if (i < 256 * 1024) h0[i] = f2bf(h0f[i]);
}

// ---- phase 1: Z = X @ Wx^T + b_ih  (bf16 out, into ZH region of d_out) ----
__global__ __launch_bounds__(256, 2) void gemm_z_kernel(
    const float* __restrict__ X, const unsigned short* __restrict__ Wx,
    const float* __restrict__ bih, unsigned short* __restrict__ Z) {
  __shared__ unsigned short As[128 * 64];
  __shared__ unsigned short Bs[128 * 64];
  const int tid = threadIdx.x, lane = tid & 63, wv = tid >> 6;
  const int m0 = (blockIdx.x >> 3) * 128;
  const int n0 = (blockIdx.x & 7) * 128;
  const int wr = (wv >> 1) * 64, wc = (wv & 1) * 64;
  f32x4 acc[4][4];
  #pragma unroll
  for (int i = 0; i < 4; i++)
    #pragma unroll
    for (int j = 0; j < 4; j++)
      #pragma unroll
      for (int r = 0; r < 4; r++) acc[i][j][r] = 0.0f;

  for (int k0 = 0; k0 < NF; k0 += 64) {
    stage_f32_to_bf16<128, 64, 256>(X + (size_t)m0 * NF + k0, NF, As, tid);
    stage_bf16<128, 64, 256>(Wx + (size_t)n0 * NF + k0, NF, Bs, tid);
    __syncthreads();
    #pragma unroll
    for (int kk = 0; kk < 64; kk += 32) {
      const int kb = kk + (lane >> 4) * 8;
      short8 af[4], bf[4];
      #pragma unroll
      for (int i = 0; i < 4; i++) af[i] = frag_ld<64>(As, wr + i * 16 + (lane & 15), kb);
      #pragma unroll
      for (int j = 0; j < 4; j++) bf[j] = frag_ld<64>(Bs, wc + j * 16 + (lane & 15), kb);
      #pragma unroll
      for (int i = 0; i < 4; i++)
        #pragma unroll
        for (int j = 0; j < 4; j++)
          acc[i][j] = __builtin_amdgcn_mfma_f32_16x16x32_bf16(af[i], bf[j], acc[i][j], 0, 0, 0);
    }
    __syncthreads();
  }
  // C/D map: col = lane&15, row = (lane>>4)*4 + r   [m89/m91]
  #pragma unroll
  for (int j = 0; j < 4; j++) {
    const int col = n0 + wc + j * 16 + (lane & 15);
    const float bv = bih[col];
    #pragma unroll
    for (int i = 0; i < 4; i++) {
      const int rbase = m0 + wr + i * 16 + ((lane >> 4) << 2);
      #pragma unroll
      for (int r = 0; r < 4; r++)
        Z[(size_t)(rbase + r) * NH + col] = f2bf(acc[i][j][r] + bv);
    }
  }
}

// ---- phase 2 (x512): h_t = tanh(Z_t + h_{t-1} @ Wh^T), in place over Z_t ----
__global__ __launch_bounds__(256, 2) void step_kernel(
    const unsigned short* __restrict__ Hp, const unsigned short* __restrict__ Wh,
    unsigned short* __restrict__ Zt) {
  __shared__ unsigned short As[64 * 64];
  __shared__ unsigned short Bs[64 * 64];
  const int tid = threadIdx.x, lane = tid & 63, wv = tid >> 6;
  const int m0 = (blockIdx.x & 3) * 64;   // batch tile
  const int n0 = (blockIdx.x >> 2) * 64;  // hid tile
  const int wr = (wv >> 1) * 32, wc = (wv & 1) * 32;
  f32x4 acc[2][2];
  #pragma unroll
  for (int i = 0; i < 2; i++)
    #pragma unroll
    for (int j = 0; j < 2; j++)
      #pragma unroll
      for (int r = 0; r < 4; r++) acc[i][j][r] = 0.0f;

  for (int k0 = 0; k0 < NH; k0 += 64) {
    stage_bf16<64, 64, 256>(Hp + (size_t)m0 * NH + k0, NH, As, tid);
    stage_bf16<64, 64, 256>(Wh + (size_t)n0 * NH + k0, NH, Bs, tid);
    __syncthreads();
    #pragma unroll
    for (int kk = 0; kk < 64; kk += 32) {
      const int kb = kk + (lane >> 4) * 8;
      short8 af[2], bf[2];
      #pragma unroll
      for (int i = 0; i < 2; i++) af[i] = frag_ld<64>(As, wr + i * 16 + (lane & 15), kb);
      #pragma unroll
      for (int j = 0; j < 2; j++) bf[j] = frag_ld<64>(Bs, wc + j * 16 + (lane & 15), kb);
      #pragma unroll
      for (int i = 0; i < 2; i++)
        #pragma unroll
        for (int j = 0; j < 2; j++)
          acc[i][j] = __builtin_amdgcn_mfma_f32_16x16x32_bf16(af[i], bf[j], acc[i][j], 0, 0, 0);
    }
    __syncthreads();
  }
  #pragma unroll
  for (int j = 0; j < 2; j++) {
    const int col = n0 + wc + j * 16 + (lane & 15);
    #pragma unroll
    for (int i = 0; i < 2; i++) {
      const int rbase = m0 + wr + i * 16 + ((lane >> 4) << 2);
      #pragma unroll
      for (int r = 0; r < 4; r++) {
        const size_t idx = (size_t)(rbase + r) * NH + col;
        float a = acc[i][j][r] + bf2f(Zt[idx]);  // Z already holds b_ih
        Zt[idx] = f2bf(fast_tanh(a));
      }
    }
  }
}

// ---- h_last copy (before phase 3 overwrites slot 511) ----
__global__ void hlast_kernel(const unsigned short* __restrict__ h, float* __restrict__ o) {
  int i = blockIdx.x * 256 + threadIdx.x;
  o[i] = bf2f(h[i]);
}

// ---- phase 3: Y = softmax(H @ Wo^T + b_ho), fused, in place over H bytes ----
__global__ __launch_bounds__(256, 2) void out_kernel(
    const unsigned short* __restrict__ H, const unsigned short* __restrict__ Wo,
    const float* __restrict__ bho, float* __restrict__ Y) {
  __shared__ unsigned short As[32 * 32];
  __shared__ unsigned short Bs[NC * 32];
  __shared__ float red[4 * 32];
  const int tid = threadIdx.x, lane = tid & 63, wv = tid >> 6;
  const int gr0 = blockIdx.x * 32;  // global row block (t*256+b space)
  f32x4 acc[2][8];
  #pragma unroll
  for (int i = 0; i < 2; i++)
    #pragma unroll
    for (int j = 0; j < 8; j++)
      #pragma unroll
      for (int r = 0; r < 4; r++) acc[i][j][r] = 0.0f;

  for (int k0 = 0; k0 < NH; k0 += 32) {
    stage_bf16<32, 32, 256>(H + (size_t)gr0 * NH + k0, NH, As, tid);
    stage_bf16<NC, 32, 256>(Wo + k0, NH, Bs, tid);
    __syncthreads();
    const int kb = (lane >> 4) * 8;
    short8 af[2], bf[8];
    #pragma unroll
    for (int i = 0; i < 2; i++) af[i] = frag_ld<32>(As, i * 16 + (lane & 15), kb);
    #pragma unroll
    for (int j = 0; j < 8; j++) bf[j] = frag_ld<32>(Bs, wv * 128 + j * 16 + (lane & 15), kb);
    #pragma unroll
    for (int i = 0; i < 2; i++)
      #pragma unroll
      for (int j = 0; j < 8; j++)
        acc[i][j] = __builtin_amdgcn_mfma_f32_16x16x32_bf16(af[i], bf[j], acc[i][j], 0, 0, 0);
    __syncthreads();
  }
  // + bias
  #pragma unroll
  for (int j = 0; j < 8; j++) {
    const float bv = bho[wv * 128 + j * 16 + (lane & 15)];
    #pragma unroll
    for (int i = 0; i < 2; i++)
      #pragma unroll
      for (int r = 0; r < 4; r++) acc[i][j][r] += bv;
  }
  // row max (per wave: 128 cols), then cross-wave via LDS
  float rmax[2][4];
  #pragma unroll
  for (int i = 0; i < 2; i++)
    #pragma unroll
    for (int r = 0; r < 4; r++) {
      float m = acc[i][0][r];
      #pragma unroll
      for (int j = 1; j < 8; j++) m = fmaxf(m, acc[i][j][r]);
      #pragma unroll
      for (int d = 1; d < 16; d <<= 1) m = fmaxf(m, __shfl_xor(m, d));
      rmax[i][r] = m;
    }
  if ((lane & 15) == 0) {
    #pragma unroll
    for (int i = 0; i < 2; i++)
      #pragma unroll
      for (int r = 0; r < 4; r++)
        red[wv * 32 + i * 16 + (lane >> 4) * 4 + r] = rmax[i][r];
  }
  __syncthreads();
  #pragma unroll
  for (int i = 0; i < 2; i++)
    #pragma unroll
    for (int r = 0; r < 4; r++) {
      const int row = i * 16 + (lane >> 4) * 4 + r;
      rmax[i][r] = fmaxf(fmaxf(red[row], red[32 + row]), fmaxf(red[64 + row], red[96 + row]));
    }
  __syncthreads();
  // exp + row sum
  float rsum[2][4];
  #pragma unroll
  for (int i = 0; i < 2; i++)
    #pragma unroll
    for (int r = 0; r < 4; r++) {
      float s = 0.0f;
      #pragma unroll
      for (int j = 0; j < 8; j++) {
        float p = __expf(acc[i][j][r] - rmax[i][r]);
        acc[i][j][r] = p;
        s += p;
      }
      #pragma unroll
      for (int d = 1; d < 16; d <<= 1) s += __shfl_xor(s, d);
      rsum[i][r] = s;
    }
  if ((lane & 15) == 0) {
    #pragma unroll
    for (int i = 0; i < 2; i++)
      #pragma unroll
      for (int r = 0; r < 4; r++)
        red[wv * 32 + i * 16 + (lane >> 4) * 4 + r] = rsum[i][r];
  }
  __syncthreads();
  #pragma unroll
  for (int i = 0; i < 2; i++)
    #pragma unroll
    for (int r = 0; r < 4; r++) {
      const int row = i * 16 + (lane >> 4) * 4 + r;
      rsum[i][r] = 1.0f / (red[row] + red[32 + row] + red[64 + row] + red[96 + row]);
    }
  // store y (in place over this WG's own H rows)
  #pragma unroll
  for (int i = 0; i < 2; i++)
    #pragma unroll
    for (int r = 0; r < 4; r++) {
      const int row = gr0 + i * 16 + (lane >> 4) * 4 + r;
      #pragma unroll
      for (int j = 0; j < 8; j++)
        Y[(size_t)row * NC + wv * 128 + j * 16 + (lane & 15)] = acc[i][j][r] * rsum[i][r];
    }
}

extern "C" void kernel_launch(void* const* d_in, const int* in_sizes, int n_in,
                              void* d_out, int out_size, void* d_ws, size_t ws_size,
                              hipStream_t stream) {
  const float* X        = (const float*)d_in[0];  // [512,256,1024]
  const float* prestate = (const float*)d_in[1];  // [256,1024]
  const float* W_ih     = (const float*)d_in[2];  // [1024,2048]
  const float* b_ih     = (const float*)d_in[3];  // [1024]
  const float* W_ho     = (const float*)d_in[4];  // [512,1024]
  const float* b_ho     = (const float*)d_in[5];  // [512]

  unsigned short* Wx = (unsigned short*)d_ws;       // 1M elems
  unsigned short* Wh = Wx + 1024 * 1024;            // 1M
  unsigned short* Wo = Wh + 1024 * 1024;            // 512K
  unsigned short* h0 = Wo + 512 * 1024;             // 256K   (total 5.5 MB of ws)

  unsigned short* ZH = (unsigned short*)d_out;      // [512,256,1024] bf16 = y region bytes
  float* out = (float*)d_out;

  prep_kernel<<<4096, 256, 0, stream>>>(W_ih, W_ho, prestate, Wx, Wh, Wo, h0);
  gemm_z_kernel<<<8192, 256, 0, stream>>>(X, Wx, b_ih, ZH);
  for (int t = 0; t < NT; ++t) {
    const unsigned short* hp = (t == 0) ? h0 : ZH + (size_t)(t - 1) * NB * NH;
    step_kernel<<<64, 256, 0, stream>>>(hp, Wh, ZH + (size_t)t * NB * NH);
  }
  hlast_kernel<<<1024, 256, 0, stream>>>(ZH + (size_t)(NT - 1) * NB * NH,
                                         out + (size_t)NT * NB * NC);
  out_kernel<<<4096, 256, 0, stream>>>(ZH, Wo, b_ho, out);
}